// Round 10
// baseline (1314.508 us; speedup 1.0000x reference)
//
#include <hip/hip_runtime.h>

#define HH 32
#define LOG2E 1.44269504088896340736f
#define KCH 32   // TF pipeline chunk length (steps per ring half)

typedef float v2f __attribute__((ext_vector_type(2)));

// ds_swizzle BitMode xor patterns, confined to 32-lane groups (and=0x1F)
#define SWZ(v, pat) __int_as_float(__builtin_amdgcn_ds_swizzle(__float_as_int(v), (pat)))

__device__ __forceinline__ float hw_exp2(float x) {
    float r; asm("v_exp_f32 %0, %1" : "=v"(r) : "v"(x)); return r;
}
__device__ __forceinline__ float sigm_e(float z, float e) {
    // 1/(1+exp2(z*e)); sigmoid(z) when e = -log2(e)
    return __builtin_amdgcn_rcpf(1.0f + hw_exp2(z * e));
}
__device__ __forceinline__ v2f pk_fma(v2f a, v2f b, v2f c) {
    return __builtin_elementwise_fma(a, b, c);   // v_pk_fma_f32, ACC operands fold
}
__device__ __forceinline__ void load_bc(const float* p, v2f* d) {
#pragma unroll
    for (int r = 0; r < 8; ++r) {                // 8x ds_read_b128, broadcast
        float4 v = ((const float4*)p)[r];
        d[2*r]   = (v2f){v.x, v.y};
        d[2*r+1] = (v2f){v.z, v.w};
    }
}

// Layout: lane l owns gate rows l (A) and l+64 (B) of the 128-row matrices.
//   l<32 : A=i[l],  B=g[l]     (channel l)
//   l>=32: A=f[l-32], B=o[l-32] (channel l-32)
// A-activation is always sigmoid; B is tanh (low lanes) / sigmoid (high lanes).
// Channel combine: f,o arrive via __shfl_xor(...,32). c/h valid on lanes<32.

__global__ __launch_bounds__(128, 2)
void lstm_seq_kernel(const float* __restrict__ input,
                     const float* __restrict__ W_ih1, const float* __restrict__ W_hh1,
                     const float* __restrict__ b_ih1, const float* __restrict__ b_hh1,
                     const float* __restrict__ W_ih2, const float* __restrict__ W_hh2,
                     const float* __restrict__ b_ih2, const float* __restrict__ b_hh2,
                     const float* __restrict__ W_lin, const float* __restrict__ b_lin,
                     float* __restrict__ out, int T, int total)
{
    const int b    = blockIdx.x;     // one block (2 waves) per batch element
    const int tid  = threadIdx.x;    // 0..127
    const int w    = tid >> 6;       // wave 0 = cell-1 producer, wave 1 = cell-2 consumer
    const int lane = tid & 63;
    const int ch   = lane & 31;
    const int rowA = lane;
    const int rowB = lane + 64;
    const bool lo  = lane < HH;

    __shared__ __align__(16) float ring[2 * KCH * HH];  // h1 stream, double-buffered
    __shared__ __align__(16) float h1x[HH];             // AR-phase h1 exchange
    __shared__ __align__(16) float h2s[HH];             // wave1 h2 self-broadcast
    __shared__ float xbuf;                              // AR feedback value

    // per-lane B-row activation constants (tanh on low lanes, sigmoid on high)
    const float esB = lo ? (-2.0f * LOG2E) : (-LOG2E);
    const float mB  = lo ? 2.0f : 1.0f;
    const float cB  = lo ? -1.0f : 0.0f;

    // ---- per-wave weights ----
    v2f m1A[16], m1B[16], m2A[16], m2B[16];
    float wxA = 0.f, wxB = 0.f, bA = 0.f, bB = 0.f, wl = 0.f, blin = 0.f;
    if (w == 0) {   // cell-1: W_hh1 rows A/B, x-weights, biases
        const v2f* pA = (const v2f*)(W_hh1 + rowA * HH);
        const v2f* pB = (const v2f*)(W_hh1 + rowB * HH);
#pragma unroll
        for (int r = 0; r < 16; ++r) { m1A[r] = pA[r]; m1B[r] = pB[r]; }
        wxA = W_ih1[rowA]; wxB = W_ih1[rowB];
        bA  = b_ih1[rowA] + b_hh1[rowA];
        bB  = b_ih1[rowB] + b_hh1[rowB];
    } else {        // cell-2: W_ih2 (m1), W_hh2 (m2), biases, W_lin
        const v2f* pA = (const v2f*)(W_ih2 + rowA * HH);
        const v2f* pB = (const v2f*)(W_ih2 + rowB * HH);
        const v2f* qA = (const v2f*)(W_hh2 + rowA * HH);
        const v2f* qB = (const v2f*)(W_hh2 + rowB * HH);
#pragma unroll
        for (int r = 0; r < 16; ++r) { m1A[r] = pA[r]; m1B[r] = pB[r];
                                       m2A[r] = qA[r]; m2B[r] = qB[r]; }
        bA  = b_ih2[rowA] + b_hh2[rowA];
        bB  = b_ih2[rowB] + b_hh2[rowB];
        wl  = W_lin[ch]; blin = b_lin[0];
    }

    float cst = 0.0f;                 // c1 (wave0) / c2 (wave1), valid lanes<32
    // wave0 carries: a = Whh1·h1(t-1)  (bias added at z1 assembly)
    v2f aA0 = {0.f,0.f}, aA1 = {0.f,0.f}, aB0 = {0.f,0.f}, aB1 = {0.f,0.f};
    // wave1 carries: e = Whh2·h2(t-1)
    v2f eA0 = {0.f,0.f}, eA1 = {0.f,0.f}, eB0 = {0.f,0.f}, eB1 = {0.f,0.f};
    v2f h2v[16];                      // persistent h2 broadcast (wave1)
#pragma unroll
    for (int r = 0; r < 16; ++r) h2v[r] = (v2f){0.f, 0.f};

    const float* __restrict__ inp  = input + (size_t)b * T;
    float* __restrict__       outp = out   + (size_t)b * total;

    // ================= Teacher-forced phase: wave-specialized pipeline ==========
    if (w == 0) {
        int t = 0;
        for (int c = 0; t < T; ++c) {
            float* buf = ring + (c & 1) * (KCH * HH);
            int S = T - t; if (S > KCH) S = KCH;
            for (int s = 0; s < S; ++s, ++t) {
                float x   = inp[t];
                float z1A = fmaf(x, wxA, bA + (aA0.x + aA0.y) + (aA1.x + aA1.y));
                float z1B = fmaf(x, wxB, bB + (aB0.x + aB0.y) + (aB1.x + aB1.y));
                float actA = sigm_e(z1A, -LOG2E);               // i | f
                float actB = fmaf(mB, sigm_e(z1B, esB), cB);    // tanh(g) | sig(o)
                float fG = __shfl_xor(actA, 32, 64);            // low: f
                float oG = __shfl_xor(actB, 32, 64);            // low: o
                cst = fmaf(fG, cst, actA * actB);
                float h1 = oG * fmaf(2.0f, sigm_e(cst, -2.0f * LOG2E), -1.0f);
                float* slot = buf + s * HH;
                if (lo) slot[lane] = h1;
                v2f h1v[16]; load_bc(slot, h1v);                // own write, in-order DS
                aA0 = (v2f){0.f,0.f}; aA1 = (v2f){0.f,0.f};
                aB0 = (v2f){0.f,0.f}; aB1 = (v2f){0.f,0.f};
#pragma unroll
                for (int r = 0; r < 16; r += 2) {
                    aA0 = pk_fma(h1v[r],   m1A[r],   aA0);
                    aA1 = pk_fma(h1v[r+1], m1A[r+1], aA1);
                    aB0 = pk_fma(h1v[r],   m1B[r],   aB0);
                    aB1 = pk_fma(h1v[r+1], m1B[r+1], aB1);
                }
            }
            __syncthreads();          // chunk c published
        }
        __syncthreads();              // match consumer's initial barrier
    } else {
        __syncthreads();              // wait for chunk 0
        int t = 0;
        for (int c = 0; t < T; ++c) {
            const float* buf = ring + (c & 1) * (KCH * HH);
            int S = T - t; if (S > KCH) S = KCH;
            for (int s = 0; s < S; ++s, ++t) {
                v2f h1v[16]; load_bc(buf + s * HH, h1v);
                v2f sA0 = eA0, sA1 = eA1, sB0 = eB0, sB1 = eB1;  // Whh2·h2(t-1)
#pragma unroll
                for (int r = 0; r < 16; r += 2) {
                    sA0 = pk_fma(h1v[r],   m1A[r],   sA0);
                    sA1 = pk_fma(h1v[r+1], m1A[r+1], sA1);
                    sB0 = pk_fma(h1v[r],   m1B[r],   sB0);
                    sB1 = pk_fma(h1v[r+1], m1B[r+1], sB1);
                }
                float z2A = bA + (sA0.x + sA0.y) + (sA1.x + sA1.y);
                float z2B = bB + (sB0.x + sB0.y) + (sB1.x + sB1.y);
                float actA = sigm_e(z2A, -LOG2E);
                float actB = fmaf(mB, sigm_e(z2B, esB), cB);
                float fG = __shfl_xor(actA, 32, 64);
                float oG = __shfl_xor(actB, 32, 64);
                cst = fmaf(fG, cst, actA * actB);
                float h2 = oG * fmaf(2.0f, sigm_e(cst, -2.0f * LOG2E), -1.0f);
                // output dot via butterfly over 32 channels (low group only)
                float p = h2 * wl;
                p += SWZ(p, 0x041F); p += SWZ(p, 0x081F); p += SWZ(p, 0x101F);
                p += SWZ(p, 0x201F); p += SWZ(p, 0x401F);
                float ov = p + blin;
                if (lane == 0) { outp[t] = ov; xbuf = ov; }
                // self-broadcast h2 and refresh e-carry for next step
                if (lo) h2s[lane] = h2;
                load_bc(h2s, h2v);
                eA0 = (v2f){0.f,0.f}; eA1 = (v2f){0.f,0.f};
                eB0 = (v2f){0.f,0.f}; eB1 = (v2f){0.f,0.f};
#pragma unroll
                for (int r = 0; r < 16; r += 2) {
                    eA0 = pk_fma(h2v[r],   m2A[r],   eA0);
                    eA1 = pk_fma(h2v[r+1], m2A[r+1], eA1);
                    eB0 = pk_fma(h2v[r],   m2B[r],   eB0);
                    eB1 = pk_fma(h2v[r+1], m2B[r+1], eB1);
                }
            }
            __syncthreads();
        }
    }

    // ================= Autoregressive phase: coupled loop, 2 barriers/step ======
    for (int t = T; t < total; ++t) {
        __syncthreads();                         // Bx: xbuf = out(t-1) visible
        if (w == 0) {
            float x   = xbuf;                    // broadcast LDS read
            float z1A = fmaf(x, wxA, bA + (aA0.x + aA0.y) + (aA1.x + aA1.y));
            float z1B = fmaf(x, wxB, bB + (aB0.x + aB0.y) + (aB1.x + aB1.y));
            float actA = sigm_e(z1A, -LOG2E);
            float actB = fmaf(mB, sigm_e(z1B, esB), cB);
            float fG = __shfl_xor(actA, 32, 64);
            float oG = __shfl_xor(actB, 32, 64);
            cst = fmaf(fG, cst, actA * actB);
            float h1 = oG * fmaf(2.0f, sigm_e(cst, -2.0f * LOG2E), -1.0f);
            if (lo) h1x[lane] = h1;
        } else {
            // shadow: e-carry from persistent h2v (overlaps wave0's act chain)
            eA0 = (v2f){0.f,0.f}; eA1 = (v2f){0.f,0.f};
            eB0 = (v2f){0.f,0.f}; eB1 = (v2f){0.f,0.f};
#pragma unroll
            for (int r = 0; r < 16; r += 2) {
                eA0 = pk_fma(h2v[r],   m2A[r],   eA0);
                eA1 = pk_fma(h2v[r+1], m2A[r+1], eA1);
                eB0 = pk_fma(h2v[r],   m2B[r],   eB0);
                eB1 = pk_fma(h2v[r+1], m2B[r+1], eB1);
            }
        }
        __syncthreads();                         // Bh: h1x visible
        if (w == 0) {
            // shadow: next z1 carry (overlaps wave1's cell-2 chain)
            v2f h1v[16]; load_bc(h1x, h1v);
            aA0 = (v2f){0.f,0.f}; aA1 = (v2f){0.f,0.f};
            aB0 = (v2f){0.f,0.f}; aB1 = (v2f){0.f,0.f};
#pragma unroll
            for (int r = 0; r < 16; r += 2) {
                aA0 = pk_fma(h1v[r],   m1A[r],   aA0);
                aA1 = pk_fma(h1v[r+1], m1A[r+1], aA1);
                aB0 = pk_fma(h1v[r],   m1B[r],   aB0);
                aB1 = pk_fma(h1v[r+1], m1B[r+1], aB1);
            }
        } else {
            v2f h1v[16]; load_bc(h1x, h1v);
            v2f sA0 = eA0, sA1 = eA1, sB0 = eB0, sB1 = eB1;
#pragma unroll
            for (int r = 0; r < 16; r += 2) {
                sA0 = pk_fma(h1v[r],   m1A[r],   sA0);
                sA1 = pk_fma(h1v[r+1], m1A[r+1], sA1);
                sB0 = pk_fma(h1v[r],   m1B[r],   sB0);
                sB1 = pk_fma(h1v[r+1], m1B[r+1], sB1);
            }
            float z2A = bA + (sA0.x + sA0.y) + (sA1.x + sA1.y);
            float z2B = bB + (sB0.x + sB0.y) + (sB1.x + sB1.y);
            float actA = sigm_e(z2A, -LOG2E);
            float actB = fmaf(mB, sigm_e(z2B, esB), cB);
            float fG = __shfl_xor(actA, 32, 64);
            float oG = __shfl_xor(actB, 32, 64);
            cst = fmaf(fG, cst, actA * actB);
            float h2 = oG * fmaf(2.0f, sigm_e(cst, -2.0f * LOG2E), -1.0f);
            float p = h2 * wl;
            p += SWZ(p, 0x041F); p += SWZ(p, 0x081F); p += SWZ(p, 0x101F);
            p += SWZ(p, 0x201F); p += SWZ(p, 0x401F);
            float ov = p + blin;
            if (lane == 0) { outp[t] = ov; xbuf = ov; }
            if (lo) h2s[lane] = h2;
            load_bc(h2s, h2v);                   // next iter's shadow e-carry input
        }
    }
}

extern "C" void kernel_launch(void* const* d_in, const int* in_sizes, int n_in,
                              void* d_out, int out_size, void* d_ws, size_t ws_size,
                              hipStream_t stream) {
    const int B = 1024;                 // fixed by the source module
    const int T = in_sizes[0] / B;      // 999
    const int total = out_size / B;     // T + future = 1999

    lstm_seq_kernel<<<dim3(B), dim3(128), 0, stream>>>(
        (const float*)d_in[0],
        (const float*)d_in[1], (const float*)d_in[2],
        (const float*)d_in[3], (const float*)d_in[4],
        (const float*)d_in[5], (const float*)d_in[6],
        (const float*)d_in[7], (const float*)d_in[8],
        (const float*)d_in[9], (const float*)d_in[10],
        (float*)d_out, T, total);
}